// Round 2
// baseline (637.109 us; speedup 1.0000x reference)
//
#include <hip/hip_runtime.h>

// Causal per-channel FIR via FFT (fft_size=16384) as packed 8192-pt complex
// FFTs. B=8, N=8192, D=512. Round 2: table twiddles (no in-loop sincos),
// scrambled-domain convolution (DIF fwd -> multiply at rev13(k) -> DIT inv,
// no permute passes), fused first/last stages in K2, K0 fused into K1 launch.

#define FFT_M 8192
#define SPEC_LEN 8193
constexpr float PI_F = 3.14159265358979323846f;

// Twiddle tables (filled by k_tw each launch; device globals avoid ws growth).
// g_tw layout (float2 units): radix-4 stages SoA w1[L],w2[L],w3[L]:
//   L=4 @0, L=16 @12, L=128 @60, L=512 @444, L=2048 @1980, end 8124;
//   radix-2 (L=64) table @8124..8187.  g_wu[k] = e^{-i pi k/8192}, k<4096.
__device__ float2 g_tw[8188];
__device__ float2 g_wu[4096];
#define TW_R2 8124

template <int L> __device__ constexpr int twbase() {
    return L == 4 ? 0 : L == 16 ? 12 : L == 128 ? 60 : L == 512 ? 444 : 1980;
}

// XOR swizzle (2-term fold) to spread power-of-2 strides across bank pairs.
__device__ __forceinline__ int swz(int k) {
    return k ^ (((k >> 4) ^ (k >> 8)) & 15);
}

// Digit reversal for radix sequence [4,4,4,2,4,4,4] (palindromic).
__device__ __forceinline__ int rev13(int k) {
    int d1 = k & 3, d2 = (k >> 2) & 3, d3 = (k >> 4) & 3, d4 = (k >> 6) & 1;
    int d5 = (k >> 7) & 3, d6 = (k >> 9) & 3, d7 = (k >> 11) & 3;
    return (d1 << 11) | (d2 << 9) | (d3 << 7) | (d4 << 6) | (d5 << 4) | (d6 << 2) | d7;
}

__device__ __forceinline__ float2 cmul(float2 a, float2 b) {
    return make_float2(a.x * b.x - a.y * b.y, a.x * b.y + a.y * b.x);
}

// DIT radix-4 stage (twiddle inputs, then butterfly). SGN=-1 fwd, +1 inv.
template <int L, int SGN>
__device__ void r4dit(float2* s, int tid) {
    #pragma unroll
    for (int t = 0; t < 4; ++t) {
        int j = tid + t * 512;
        int pos = j & (L - 1);
        int i0 = 4 * (j - pos) + pos;
        float2 a = s[swz(i0)];
        float2 b = s[swz(i0 + L)];
        float2 c = s[swz(i0 + 2 * L)];
        float2 d = s[swz(i0 + 3 * L)];
        if constexpr (L > 1) {
            constexpr int B = twbase<L>();
            float2 w1 = g_tw[B + pos], w2 = g_tw[B + L + pos], w3 = g_tw[B + 2 * L + pos];
            if constexpr (SGN > 0) { w1.y = -w1.y; w2.y = -w2.y; w3.y = -w3.y; }
            b = cmul(b, w1); c = cmul(c, w2); d = cmul(d, w3);
        }
        float2 t0 = make_float2(a.x + c.x, a.y + c.y);
        float2 t1 = make_float2(a.x - c.x, a.y - c.y);
        float2 t2 = make_float2(b.x + d.x, b.y + d.y);
        float2 t3 = make_float2(b.x - d.x, b.y - d.y);
        float2 j3 = (SGN < 0) ? make_float2(t3.y, -t3.x) : make_float2(-t3.y, t3.x);
        s[swz(i0)]         = make_float2(t0.x + t2.x, t0.y + t2.y);
        s[swz(i0 + L)]     = make_float2(t1.x + j3.x, t1.y + j3.y);
        s[swz(i0 + 2 * L)] = make_float2(t0.x - t2.x, t0.y - t2.y);
        s[swz(i0 + 3 * L)] = make_float2(t1.x - j3.x, t1.y - j3.y);
    }
    __syncthreads();
}

// DIF radix-4 stage (butterfly, then twiddle outputs).
template <int L, int SGN>
__device__ void r4dif(float2* s, int tid) {
    #pragma unroll
    for (int t = 0; t < 4; ++t) {
        int j = tid + t * 512;
        int pos = j & (L - 1);
        int i0 = 4 * (j - pos) + pos;
        float2 a = s[swz(i0)];
        float2 b = s[swz(i0 + L)];
        float2 c = s[swz(i0 + 2 * L)];
        float2 d = s[swz(i0 + 3 * L)];
        float2 t0 = make_float2(a.x + c.x, a.y + c.y);
        float2 t1 = make_float2(a.x - c.x, a.y - c.y);
        float2 t2 = make_float2(b.x + d.x, b.y + d.y);
        float2 t3 = make_float2(b.x - d.x, b.y - d.y);
        float2 j3 = (SGN < 0) ? make_float2(t3.y, -t3.x) : make_float2(-t3.y, t3.x);
        float2 u0 = make_float2(t0.x + t2.x, t0.y + t2.y);
        float2 u1 = make_float2(t1.x + j3.x, t1.y + j3.y);
        float2 u2 = make_float2(t0.x - t2.x, t0.y - t2.y);
        float2 u3 = make_float2(t1.x - j3.x, t1.y - j3.y);
        if constexpr (L > 1) {
            constexpr int B = twbase<L>();
            float2 w1 = g_tw[B + pos], w2 = g_tw[B + L + pos], w3 = g_tw[B + 2 * L + pos];
            if constexpr (SGN > 0) { w1.y = -w1.y; w2.y = -w2.y; w3.y = -w3.y; }
            u1 = cmul(u1, w1); u2 = cmul(u2, w2); u3 = cmul(u3, w3);
        }
        s[swz(i0)]         = u0;
        s[swz(i0 + L)]     = u1;
        s[swz(i0 + 2 * L)] = u2;
        s[swz(i0 + 3 * L)] = u3;
    }
    __syncthreads();
}

template <int SGN>
__device__ void r2dit(float2* s, int tid) {
    #pragma unroll
    for (int t = 0; t < 8; ++t) {
        int j = tid + t * 512;
        int pos = j & 63;
        int i0 = 2 * (j - pos) + pos;
        float2 a = s[swz(i0)];
        float2 b = s[swz(i0 + 64)];
        float2 w = g_tw[TW_R2 + pos];
        if constexpr (SGN > 0) w.y = -w.y;
        float2 wb = cmul(b, w);
        s[swz(i0)]      = make_float2(a.x + wb.x, a.y + wb.y);
        s[swz(i0 + 64)] = make_float2(a.x - wb.x, a.y - wb.y);
    }
    __syncthreads();
}

template <int SGN>
__device__ void r2dif(float2* s, int tid) {
    #pragma unroll
    for (int t = 0; t < 8; ++t) {
        int j = tid + t * 512;
        int pos = j & 63;
        int i0 = 2 * (j - pos) + pos;
        float2 a = s[swz(i0)];
        float2 b = s[swz(i0 + 64)];
        float2 w = g_tw[TW_R2 + pos];
        if constexpr (SGN > 0) w.y = -w.y;
        float2 dd = make_float2(a.x - b.x, a.y - b.y);
        s[swz(i0)]      = make_float2(a.x + b.x, a.y + b.y);
        s[swz(i0 + 64)] = cmul(dd, w);
    }
    __syncthreads();
}

// Full FFT cores. DIF: natural in -> bin k at rev13(k). DIT: bin j at
// rev13(j) in -> natural out. (Palindromic radices => same rev13 both ways.)
template <int SGN> __device__ void fft_dif_full(float2* s, int tid) {
    r4dif<2048, SGN>(s, tid); r4dif<512, SGN>(s, tid); r4dif<128, SGN>(s, tid);
    r2dif<SGN>(s, tid);
    r4dif<16, SGN>(s, tid); r4dif<4, SGN>(s, tid); r4dif<1, SGN>(s, tid);
}
template <int SGN> __device__ void fft_dit_full(float2* s, int tid) {
    r4dit<1, SGN>(s, tid); r4dit<4, SGN>(s, tid); r4dit<16, SGN>(s, tid);
    r2dit<SGN>(s, tid);
    r4dit<128, SGN>(s, tid); r4dit<512, SGN>(s, tid); r4dit<2048, SGN>(s, tid);
}

// Twiddle table setup (runs every launch; tiny).
__global__ __launch_bounds__(512) void k_tw() {
    int gid = blockIdx.x * 512 + threadIdx.x;
    for (int idx = gid; idx < 8188 + 4096; idx += gridDim.x * 512) {
        if (idx < 8124) {
            int L, B;
            if (idx < 12)        { L = 4;    B = 0; }
            else if (idx < 60)   { L = 16;   B = 12; }
            else if (idx < 444)  { L = 128;  B = 60; }
            else if (idx < 1980) { L = 512;  B = 444; }
            else                 { L = 2048; B = 1980; }
            int q = idx - B;
            int m = q / L + 1;            // 1,2,3 -> w^m
            int pos = q - (m - 1) * L;
            float ang = -2.0f * PI_F * (float)(m * pos) / (4.0f * (float)L);
            g_tw[idx] = make_float2(cosf(ang), sinf(ang));
        } else if (idx < 8188) {
            int pos = idx - 8124;
            float ang = -2.0f * PI_F * (float)pos / 128.0f;
            g_tw[idx] = make_float2(cosf(ang), sinf(ang));
        } else {
            int k = idx - 8188;
            float ang = -PI_F * (float)k / 8192.0f;
            g_wu[k] = make_float2(cosf(ang), sinf(ang));
        }
    }
}

// Linear interp of coeffs (512 -> 8192, half-pixel), a[0]=dc.
__device__ __forceinline__ float aval(const float* C, float dcv, int idx) {
    if (idx == 0) return dcv;
    int j = idx - 1;
    float src = ((float)j + 0.5f) * 0.0625f - 0.5f;
    src = fminf(fmaxf(src, 0.0f), 511.0f);
    int lo = (int)floorf(src);
    int hi = min(lo + 1, 511);
    float w = src - (float)lo;
    return C[lo] * (1.0f - w) + C[hi] * w;
}

// Fused kernel: blocks [0,512) build spec[d]; blocks [512,512+16384) pack x.
__global__ __launch_bounds__(512) void k01(const float* __restrict__ x,
                                           const float* __restrict__ coeffs,
                                           const float* __restrict__ dc,
                                           float2* __restrict__ spec,
                                           float2* __restrict__ zin) {
    __shared__ float2 sbuf[FFT_M];
    int tid = threadIdx.x;
    if (blockIdx.x < 512) {
        int d = blockIdx.x;
        const float* C = coeffs + d * 512;
        float dcv = dc[d];
        // Z_A[k] written directly to rev13(k) (DIT input order)
        #pragma unroll
        for (int t = 0; t < 16; ++t) {
            int k = tid + t * 512;
            float ak = aval(C, dcv, k);
            float am = aval(C, dcv, 8192 - k);
            float Ae = 0.5f * (ak + am);
            float Ao = 0.5f * (ak - am);
            float sn, cs;
            __sincosf((PI_F / 8192.0f) * (float)k, &sn, &cs);
            sbuf[swz(rev13(k))] = make_float2(Ae - Ao * sn, Ao * cs);
        }
        __syncthreads();
        fft_dit_full<1>(sbuf, tid);        // inverse -> time domain (natural)
        #pragma unroll
        for (int t = 0; t < 16; ++t) {     // causal Hilbert window + repack
            int n = tid + t * 512;
            float2 z = sbuf[swz(n)];
            float te = z.x * (1.0f / 8192.0f);
            float to = z.y * (1.0f / 8192.0f);
            int m0 = 2 * n;
            float he = (m0 == 0) ? te : ((m0 < 8192) ? 2.0f * te : ((m0 == 8192) ? te : 0.0f));
            float ho = (m0 + 1 < 8192) ? 2.0f * to : 0.0f;
            sbuf[swz(n)] = make_float2(he, ho);
        }
        __syncthreads();
        fft_dif_full<-1>(sbuf, tid);       // forward -> scrambled bins
        float2* Sd = spec + (size_t)d * SPEC_LEN;
        const float scale = 1.0f / 8192.0f;
        #pragma unroll
        for (int t = 0; t < 8; ++t) {
            int k = tid + t * 512;
            if (k == 0) {
                float2 Z0 = sbuf[0];                    // rev13(0)=0
                Sd[0]    = make_float2((Z0.x + Z0.y) * scale, 0.0f);
                Sd[8192] = make_float2((Z0.x - Z0.y) * scale, 0.0f);
                float2 Z4 = sbuf[swz(rev13(4096))];
                Sd[4096] = make_float2(Z4.x * scale, -Z4.y * scale);
            } else {
                int km = 8192 - k;
                float2 Zk = sbuf[swz(rev13(k))];
                float2 Zm = sbuf[swz(rev13(km))];
                float2 Xe = make_float2((Zk.x + Zm.x) * 0.5f, (Zk.y - Zm.y) * 0.5f);
                float2 dz = make_float2((Zk.x - Zm.x) * 0.5f, (Zk.y + Zm.y) * 0.5f);
                float2 Xo = make_float2(dz.y, -dz.x);
                float2 w = g_wu[k];
                float2 wXo = cmul(w, Xo);
                Sd[k]  = make_float2((Xe.x + wXo.x) * scale, (Xe.y + wXo.y) * scale);
                Sd[km] = make_float2((Xe.x - wXo.x) * scale, -(Xe.y - wXo.y) * scale);
            }
        }
    } else {
        // pack/transpose: x(B,N,D) -> zin[(d*8+b)][n'] = x[b][2n'][d] + i x[b][2n'+1][d]
        int bid = blockIdx.x - 512;
        int nt = bid & 127, dt = (bid >> 7) & 15, bb = bid >> 11;
        float* tile = (float*)sbuf;        // [64][33]
        int tx = tid & 31, ty = tid >> 5;  // ty 0..15
        const float* xb = x + (size_t)bb * 8192 * 512;
        int n0 = nt * 64, d0 = dt * 32;
        #pragma unroll
        for (int r = 0; r < 4; ++r) {
            int row = ty + r * 16;
            tile[row * 33 + tx] = xb[(size_t)(n0 + row) * 512 + d0 + tx];
        }
        __syncthreads();
        #pragma unroll
        for (int r = 0; r < 2; ++r) {
            int dl = ty + r * 16;
            int d  = d0 + dl;
            int np = nt * 32 + tx;
            float2 v = make_float2(tile[(2 * tx) * 33 + dl], tile[(2 * tx + 1) * 33 + dl]);
            zin[((size_t)(d * 8 + bb)) * 4096 + np] = v;
        }
    }
}

// K2: fused-load DIF -> scrambled multiply -> DIT -> fused-store (first half).
__global__ __launch_bounds__(512) void k2_conv(const float2* __restrict__ zin,
                                               const float2* __restrict__ spec,
                                               float2* __restrict__ yout) {
    __shared__ float2 sbuf[FFT_M];
    int wg = blockIdx.x, d = wg >> 3, tid = threadIdx.x;
    const float2* zi = zin + (size_t)wg * 4096;
    // first DIF stage (L=2048, SGN=-1) fused with global load; c=d=0 (zero pad)
    #pragma unroll
    for (int t = 0; t < 4; ++t) {
        int pos = tid + t * 512;
        float2 a = zi[pos];
        float2 b = zi[pos + 2048];
        constexpr int B = twbase<2048>();
        float2 w1 = g_tw[B + pos], w2 = g_tw[B + 2048 + pos], w3 = g_tw[B + 4096 + pos];
        float2 u1 = make_float2(a.x + b.y, a.y - b.x);   // a + i*(-1)*b
        float2 u2 = make_float2(a.x - b.x, a.y - b.y);
        float2 u3 = make_float2(a.x - b.y, a.y + b.x);
        sbuf[swz(pos)]        = make_float2(a.x + b.x, a.y + b.y);
        sbuf[swz(pos + 2048)] = cmul(u1, w1);
        sbuf[swz(pos + 4096)] = cmul(u2, w2);
        sbuf[swz(pos + 6144)] = cmul(u3, w3);
    }
    __syncthreads();
    r4dif<512, -1>(sbuf, tid); r4dif<128, -1>(sbuf, tid);
    r2dif<-1>(sbuf, tid);
    r4dif<16, -1>(sbuf, tid); r4dif<4, -1>(sbuf, tid); r4dif<1, -1>(sbuf, tid);
    // unpack -> *spec -> repack, in scrambled positions
    const float2* S = spec + (size_t)d * SPEC_LEN;
    #pragma unroll
    for (int t = 0; t < 8; ++t) {
        int k = tid + t * 512;
        if (k == 0) {
            float2 Z0 = sbuf[0];
            float X0 = Z0.x + Z0.y, XM = Z0.x - Z0.y;
            float2 S0 = S[0], SM = S[8192];
            float2 Y0 = make_float2(X0 * S0.x, X0 * S0.y);
            float2 YM = make_float2(XM * SM.x, XM * SM.y);
            float2 Ye = make_float2((Y0.x + YM.x) * 0.5f, (Y0.y - YM.y) * 0.5f);
            float2 Yo = make_float2((Y0.x - YM.x) * 0.5f, (Y0.y + YM.y) * 0.5f);
            sbuf[0] = make_float2(Ye.x - Yo.y, Ye.y + Yo.x);
            int p4 = swz(rev13(4096));
            float2 Z4 = sbuf[p4];
            float2 Y4 = cmul(make_float2(Z4.x, -Z4.y), S[4096]);
            sbuf[p4] = make_float2(Y4.x, -Y4.y);
        } else {
            int km = 8192 - k;
            int p1 = swz(rev13(k)), p2 = swz(rev13(km));
            float2 Zk = sbuf[p1], Zm = sbuf[p2];
            float2 Xe = make_float2((Zk.x + Zm.x) * 0.5f, (Zk.y - Zm.y) * 0.5f);
            float2 dz = make_float2((Zk.x - Zm.x) * 0.5f, (Zk.y + Zm.y) * 0.5f);
            float2 Xo = make_float2(dz.y, -dz.x);
            float2 w = g_wu[k];                           // e^{-i pi k/M}
            float2 wXo = cmul(w, Xo);
            float2 Xk = make_float2(Xe.x + wXo.x, Xe.y + wXo.y);
            float2 Xm = make_float2(Xe.x - wXo.x, -(Xe.y - wXo.y));
            float2 Yk = cmul(Xk, S[k]);
            float2 Ym = cmul(Xm, S[km]);
            float2 Ye = make_float2((Yk.x + Ym.x) * 0.5f, (Yk.y - Ym.y) * 0.5f);
            float2 dy = make_float2((Yk.x - Ym.x) * 0.5f, (Yk.y + Ym.y) * 0.5f);
            float2 Yo = cmul(make_float2(w.x, -w.y), dy); // *e^{+i pi k/M}
            sbuf[p1] = make_float2(Ye.x - Yo.y, Ye.y + Yo.x);
            sbuf[p2] = make_float2(Ye.x + Yo.y, Yo.x - Ye.y);
        }
    }
    __syncthreads();
    r4dit<1, 1>(sbuf, tid); r4dit<4, 1>(sbuf, tid); r4dit<16, 1>(sbuf, tid);
    r2dit<1>(sbuf, tid);
    r4dit<128, 1>(sbuf, tid); r4dit<512, 1>(sbuf, tid);
    // last DIT stage (L=2048, SGN=+1) fused with store; only outputs 0,1 needed
    float2* yo = yout + (size_t)wg * 4096;
    #pragma unroll
    for (int t = 0; t < 4; ++t) {
        int pos = tid + t * 512;
        float2 a  = sbuf[swz(pos)];
        float2 b  = sbuf[swz(pos + 2048)];
        float2 c  = sbuf[swz(pos + 4096)];
        float2 dd = sbuf[swz(pos + 6144)];
        constexpr int B = twbase<2048>();
        float2 w1 = g_tw[B + pos], w2 = g_tw[B + 2048 + pos], w3 = g_tw[B + 4096 + pos];
        w1.y = -w1.y; w2.y = -w2.y; w3.y = -w3.y;
        b = cmul(b, w1); c = cmul(c, w2); dd = cmul(dd, w3);
        float2 t0 = make_float2(a.x + c.x, a.y + c.y);
        float2 t1 = make_float2(a.x - c.x, a.y - c.y);
        float2 t2 = make_float2(b.x + dd.x, b.y + dd.y);
        float2 t3 = make_float2(b.x - dd.x, b.y - dd.y);
        float2 j3 = make_float2(-t3.y, t3.x);
        yo[pos]        = make_float2(t0.x + t2.x, t0.y + t2.y);
        yo[pos + 2048] = make_float2(t1.x + j3.x, t1.y + j3.y);
    }
}

// K3: yout[(d*8+b)][n'] -> out[b][2n'][d], out[b][2n'+1][d]
__global__ __launch_bounds__(256) void k3_unpack(const float2* __restrict__ yout,
                                                 float* __restrict__ out) {
    __shared__ float2 tile[32][33];
    int bb = blockIdx.z, nt = blockIdx.x, dt = blockIdx.y;
    int tx = threadIdx.x & 31, ty = threadIdx.x >> 5;
    int d0 = dt * 32, np0 = nt * 32;
    #pragma unroll
    for (int r = 0; r < 4; ++r) {
        int dl = ty + r * 8;
        tile[dl][tx] = yout[((size_t)((d0 + dl) * 8 + bb)) * 4096 + np0 + tx];
    }
    __syncthreads();
    float* ob = out + (size_t)bb * 8192 * 512;
    #pragma unroll
    for (int r = 0; r < 4; ++r) {
        int nl = ty + r * 8;
        int n  = np0 + nl;
        float2 v = tile[tx][nl];
        ob[(size_t)(2 * n) * 512 + d0 + tx]     = v.x;
        ob[(size_t)(2 * n + 1) * 512 + d0 + tx] = v.y;
    }
}

extern "C" void kernel_launch(void* const* d_in, const int* in_sizes, int n_in,
                              void* d_out, int out_size, void* d_ws, size_t ws_size,
                              hipStream_t stream) {
    const float* x      = (const float*)d_in[0];   // (8, 8192, 512)
    const float* coeffs = (const float*)d_in[1];   // (512, 512)
    const float* dc     = (const float*)d_in[2];   // (512, 1)
    float* out = (float*)d_out;                    // (8, 8192, 512)

    float2* spec = (float2*)d_ws;                                  // 512*8193 f2
    float2* zbuf = (float2*)((char*)d_ws + (size_t)512 * SPEC_LEN * sizeof(float2)); // 4096*4096 f2

    k_tw<<<24, 512, 0, stream>>>();
    k01<<<512 + 16384, 512, 0, stream>>>(x, coeffs, dc, spec, zbuf);
    k2_conv<<<4096, 512, 0, stream>>>(zbuf, spec, zbuf);   // in-place per-wg
    k3_unpack<<<dim3(128, 16, 8), 256, 0, stream>>>(zbuf, out);
}

// Round 3
// 529.111 us; speedup vs baseline: 1.2041x; 1.2041x over previous
//
#include <hip/hip_runtime.h>

// Causal per-channel FIR via FFT (fft_size=16384) as packed 8192-pt complex
// FFTs. B=8, N=8192, D=512. Round 3: register-resident four-step FFT
// (8192 = 16 x 16 x 32): 16-pt FFTs in VGPRs, radix-32 tail via lane-pair
// shfl_xor, only 6 LDS exchanges per conv (was ~15). All twiddles from
// compile-time constants + per-thread sincos base with chained cmul.
// LDS layouts use rotated-low-digit addressing: conflict-free at the
// 16-lane b64 phase granularity, exactly 64 KB (2 blocks/CU).

#define SPEC_LEN 8193
constexpr float PI_F = 3.14159265358979323846f;

__device__ __forceinline__ float2 f2add(float2 a, float2 b) { return make_float2(a.x + b.x, a.y + b.y); }
__device__ __forceinline__ float2 f2sub(float2 a, float2 b) { return make_float2(a.x - b.x, a.y - b.y); }
__device__ __forceinline__ float2 cmul(float2 a, float2 b) {
    return make_float2(a.x * b.x - a.y * b.y, a.x * b.y + a.y * b.x);
}

// FFT16 leaves output X[k] in v[SLOT(k)]
#define SLOT(k) ((((k) & 3) << 2) | ((k) >> 2))

// LDS layouts (float2-element units, all within [0,8192)):
// bank-pair of a b64 access = (addr & 15); each layout keeps the lane-varying
// digit in the low nibble (rotated) so every 16-lane phase hits 16 distinct
// bank pairs.
__device__ __forceinline__ int addr1(int n2, int k1) {            // A[k1, n2]
    return (n2 << 4) | ((k1 + n2) & 15);
}
__device__ __forceinline__ int addr2(int r, int m2) {             // B[r=(k1*16+q1), m2]
    return (r << 5) | ((m2 + 2 * r) & 31);
}
__device__ __forceinline__ int addr3(int k) {                     // X[k], k natural bin
    int lo = (k + 2 * (k >> 4) + (k >> 8) + (k >> 12)) & 15;
    return (k & ~15) | lo;
}

// radix-4 butterfly. SGN=-1 forward (e^{-i}), +1 inverse.
template <int SGN>
__device__ __forceinline__ void fft4(float2& a, float2& b, float2& c, float2& d) {
    float2 A0 = f2add(a, c), A1 = f2sub(a, c), A2 = f2add(b, d), A3 = f2sub(b, d);
    float2 T = (SGN < 0) ? make_float2(A3.y, -A3.x) : make_float2(-A3.y, A3.x);
    a = f2add(A0, A2); b = f2add(A1, T); c = f2sub(A0, A2); d = f2sub(A1, T);
}

template <int SGN>
__device__ __forceinline__ void fft16_tail(float2* v) {
    const float C1 = 0.9238795325112867f, S1 = 0.3826834323650898f, R2 = 0.7071067811865476f;
    v[5]  = cmul(v[5],  make_float2(C1, SGN < 0 ? -S1 : S1));
    v[6]  = cmul(v[6],  make_float2(R2, SGN < 0 ? -R2 : R2));
    v[7]  = cmul(v[7],  make_float2(S1, SGN < 0 ? -C1 : C1));
    v[9]  = cmul(v[9],  make_float2(R2, SGN < 0 ? -R2 : R2));
    v[10] = (SGN < 0) ? make_float2(v[10].y, -v[10].x) : make_float2(-v[10].y, v[10].x);
    v[11] = cmul(v[11], make_float2(-R2, SGN < 0 ? -R2 : R2));
    v[13] = cmul(v[13], make_float2(S1, SGN < 0 ? -C1 : C1));
    v[14] = cmul(v[14], make_float2(-R2, SGN < 0 ? -R2 : R2));
    v[15] = cmul(v[15], make_float2(-C1, SGN < 0 ? S1 : -S1));
    fft4<SGN>(v[0], v[1], v[2], v[3]);
    fft4<SGN>(v[4], v[5], v[6], v[7]);
    fft4<SGN>(v[8], v[9], v[10], v[11]);
    fft4<SGN>(v[12], v[13], v[14], v[15]);
}
template <int SGN>
__device__ __forceinline__ void fft16(float2* v) {   // natural in, X[k] at SLOT(k)
    fft4<SGN>(v[0], v[4], v[8], v[12]);
    fft4<SGN>(v[1], v[5], v[9], v[13]);
    fft4<SGN>(v[2], v[6], v[10], v[14]);
    fft4<SGN>(v[3], v[7], v[11], v[15]);
    fft16_tail<SGN>(v);
}
template <int SGN>
__device__ __forceinline__ void fft16_half(float2* v) {  // v[0..7] in, upper half = 0
    #pragma unroll
    for (int j = 0; j < 4; ++j) {
        float2 a = v[j], b = v[j + 4];
        float2 T = (SGN < 0) ? make_float2(b.y, -b.x) : make_float2(-b.y, b.x);
        v[j] = f2add(a, b); v[j + 4] = f2add(a, T);
        v[j + 8] = f2sub(a, b); v[j + 12] = f2sub(a, T);
    }
    fft16_tail<SGN>(v);
}

// v[SLOT(k)] *= w^k, k=1..15 (applied to FFT outputs)
__device__ __forceinline__ void twchain(float2* v, float2 w) {
    float2 acc = w;
    v[SLOT(1)] = cmul(v[SLOT(1)], acc);
    #pragma unroll
    for (int k = 2; k < 16; ++k) { acc = cmul(acc, w); v[SLOT(k)] = cmul(v[SLOT(k)], acc); }
}
// v[k] *= w^k, k=1..15 (applied to IFFT inputs, natural index)
__device__ __forceinline__ void twchain_nat(float2* v, float2 w) {
    float2 acc = w;
    v[1] = cmul(v[1], acc);
    #pragma unroll
    for (int k = 2; k < 16; ++k) { acc = cmul(acc, w); v[k] = cmul(v[k], acc); }
}

__device__ __forceinline__ float2 shflx1(float2 v) {
    return make_float2(__shfl_xor(v.x, 1), __shfl_xor(v.y, 1));
}

#define W32_TABLES \
    constexpr float WC[16] = {1.f, 0.98078528f, 0.92387953f, 0.83146961f, 0.70710678f, \
        0.55557023f, 0.38268343f, 0.19509032f, 0.f, -0.19509032f, -0.38268343f, \
        -0.55557023f, -0.70710678f, -0.83146961f, -0.92387953f, -0.98078528f}; \
    constexpr float WS[16] = {0.f, 0.19509032f, 0.38268343f, 0.55557023f, 0.70710678f, \
        0.83146961f, 0.92387953f, 0.98078528f, 1.f, 0.98078528f, 0.92387953f, \
        0.83146961f, 0.70710678f, 0.55557023f, 0.38268343f, 0.19509032f};

// Forward levels 2+3: LDS1 (A[k1,n2] synced) -> ... -> LDS3 (X[k] at addr3), synced.
__device__ __forceinline__ void fwd_L2_L3(float2* sbuf, int tid) {
    {   // L2: 16-pt FFT over m1 for each (k1, m2), twiddle W_512^{m2 q1}
        int k1 = tid >> 5, m2 = tid & 31;
        float2 u[16];
        #pragma unroll
        for (int m1 = 0; m1 < 16; ++m1) u[m1] = sbuf[addr1(32 * m1 + m2, k1)];
        __syncthreads();
        fft16<-1>(u);
        float sn, cs; __sincosf(-(PI_F / 256.0f) * (float)m2, &sn, &cs);
        twchain(u, make_float2(cs, sn));
        #pragma unroll
        for (int q1 = 0; q1 < 16; ++q1) sbuf[addr2(k1 * 16 + q1, m2)] = u[SLOT(q1)];
        __syncthreads();
    }
    {   // L3: 32-pt FFT over m2 for each (k1,q1): paired threads, shfl combine
        int k1 = tid >> 5, q1 = (tid >> 1) & 15, half = tid & 1;
        float2 e[16];
        #pragma unroll
        for (int j = 0; j < 16; ++j) e[j] = sbuf[addr2(k1 * 16 + q1, 2 * j + half)];
        __syncthreads();
        fft16<-1>(e);
        W32_TABLES
        #pragma unroll
        for (int q = 0; q < 16; ++q) {
            float2 mine = e[SLOT(q)];
            float2 othr = shflx1(mine);
            float2 Eq = half ? othr : mine;
            float2 Oq = half ? mine : othr;
            float2 WO = cmul(make_float2(WC[q], -WS[q]), Oq);
            float2 X = half ? f2sub(Eq, WO) : f2add(Eq, WO);
            int k = k1 + 16 * q1 + 256 * (q + 16 * half);
            sbuf[addr3(k)] = X;
        }
        __syncthreads();
    }
}

// Inverse levels 3+2: LDS3 (Y[k] at addr3, synced) -> ... -> LDS1 (A'[k1,n2]), synced.
__device__ __forceinline__ void inv_L3_L2(float2* sbuf, int tid) {
    {   // inv L3
        int k1 = tid >> 5, q1 = (tid >> 1) & 15, half = tid & 1;
        float2 t[16];
        #pragma unroll
        for (int q = 0; q < 16; ++q)
            t[q] = sbuf[addr3(k1 + 16 * q1 + 256 * (q + 16 * half))];
        __syncthreads();
        W32_TABLES
        #pragma unroll
        for (int q = 0; q < 16; ++q) {
            float2 othr = shflx1(t[q]);
            if (half) t[q] = cmul(make_float2(WC[q], WS[q]), f2sub(othr, t[q]));
            else      t[q] = f2add(t[q], othr);
        }
        fft16<1>(t);
        #pragma unroll
        for (int j = 0; j < 16; ++j) sbuf[addr2(k1 * 16 + q1, 2 * j + half)] = t[SLOT(j)];
        __syncthreads();
    }
    {   // inv L2
        int k1 = tid >> 5, m2 = tid & 31;
        float2 u[16];
        #pragma unroll
        for (int q1 = 0; q1 < 16; ++q1) u[q1] = sbuf[addr2(k1 * 16 + q1, m2)];
        __syncthreads();
        float sn, cs; __sincosf((PI_F / 256.0f) * (float)m2, &sn, &cs);
        twchain_nat(u, make_float2(cs, sn));
        fft16<1>(u);
        #pragma unroll
        for (int m1 = 0; m1 < 16; ++m1) sbuf[addr1(32 * m1 + m2, k1)] = u[SLOT(m1)];
        __syncthreads();
    }
}

// Inverse level 1: LDS1 -> registers, y[n1] at v[SLOT(n1)] (unnormalized).
__device__ __forceinline__ void inv_L1(const float2* sbuf, int tid, float2* v) {
    #pragma unroll
    for (int k1 = 0; k1 < 16; ++k1) v[k1] = sbuf[addr1(tid, k1)];
    float sn, cs; __sincosf((PI_F / 4096.0f) * (float)tid, &sn, &cs);
    twchain_nat(v, make_float2(cs, sn));
    fft16<1>(v);
}

// Linear interp of coeffs (512 -> 8192, half-pixel), a[0]=dc.
__device__ __forceinline__ float aval(const float* C, float dcv, int idx) {
    if (idx == 0) return dcv;
    int j = idx - 1;
    float src = ((float)j + 0.5f) * 0.0625f - 0.5f;
    src = fminf(fmaxf(src, 0.0f), 511.0f);
    int lo = (int)floorf(src);
    int hi = min(lo + 1, 511);
    float w = src - (float)lo;
    return C[lo] * (1.0f - w) + C[hi] * w;
}

// Fused: blocks [0,512) build spec[d]; blocks [512, 512+8192) transpose/pack x.
__global__ __launch_bounds__(512) void k01(const float* __restrict__ x,
                                           const float* __restrict__ coeffs,
                                           const float* __restrict__ dc,
                                           float2* __restrict__ spec,
                                           float2* __restrict__ zin) {
    __shared__ float2 sbuf[8192];
    int tid = threadIdx.x;
    if (blockIdx.x < 512) {
        int d = blockIdx.x;
        const float* C = coeffs + d * 512;
        float dcv = dc[d];
        // Z_A[k] = Ae + i*Ao*e^{+i pi k/M}  (packed-irfft spectrum), into LDS3
        #pragma unroll
        for (int tt = 0; tt < 16; ++tt) {
            int k = tid + (tt << 9);
            float ak = aval(C, dcv, k);
            float am = aval(C, dcv, 8192 - k);
            float Ae = 0.5f * (ak + am), Ao = 0.5f * (ak - am);
            float sn, cs; __sincosf((PI_F / 8192.0f) * (float)k, &sn, &cs);
            sbuf[addr3(k)] = make_float2(Ae - Ao * sn, Ao * cs);
        }
        __syncthreads();
        inv_L3_L2(sbuf, tid);
        float2 v[16];
        inv_L1(sbuf, tid, v);          // packed time, x8192 scale
        // causal Hilbert window + renormalize; reorder to natural n1
        float2 u[16];
        #pragma unroll
        for (int n1 = 0; n1 < 16; ++n1) {
            float2 z = v[SLOT(n1)];
            int n = (n1 << 9) + tid;
            float te = z.x * (1.0f / 8192.0f);
            float to = z.y * (1.0f / 8192.0f);
            int m0 = 2 * n;
            float he = (m0 == 0) ? te : ((m0 < 8192) ? 2.0f * te : ((m0 == 8192) ? te : 0.0f));
            float ho = (m0 + 1 < 8192) ? 2.0f * to : 0.0f;
            u[n1] = make_float2(he, ho);
        }
        // forward L1 (full): same-row rewrite of LDS1, no barrier needed before
        fft16<-1>(u);
        float sn, cs; __sincosf(-(PI_F / 4096.0f) * (float)tid, &sn, &cs);
        twchain(u, make_float2(cs, sn));
        #pragma unroll
        for (int k1 = 0; k1 < 16; ++k1) sbuf[addr1(tid, k1)] = u[SLOT(k1)];
        __syncthreads();
        fwd_L2_L3(sbuf, tid);
        // unpack packed-real FFT -> spec (scale folds K2's inverse 1/8192)
        float2* Sd = spec + (size_t)d * SPEC_LEN;
        const float scale = 1.0f / 8192.0f;
        #pragma unroll
        for (int tt = 0; tt < 8; ++tt) {
            int k = tid + (tt << 9);
            if (k == 0) {
                float2 Z0 = sbuf[addr3(0)];
                Sd[0]    = make_float2((Z0.x + Z0.y) * scale, 0.0f);
                Sd[8192] = make_float2((Z0.x - Z0.y) * scale, 0.0f);
                float2 Z4 = sbuf[addr3(4096)];
                Sd[4096] = make_float2(Z4.x * scale, -Z4.y * scale);
            } else {
                int km = 8192 - k;
                float2 Zk = sbuf[addr3(k)], Zm = sbuf[addr3(km)];
                float2 Xe = make_float2((Zk.x + Zm.x) * 0.5f, (Zk.y - Zm.y) * 0.5f);
                float2 dz = make_float2((Zk.x - Zm.x) * 0.5f, (Zk.y + Zm.y) * 0.5f);
                float2 Xo = make_float2(dz.y, -dz.x);
                float sn2, cs2; __sincosf(-(PI_F / 8192.0f) * (float)k, &sn2, &cs2);
                float2 wXo = cmul(make_float2(cs2, sn2), Xo);
                Sd[k]  = make_float2((Xe.x + wXo.x) * scale, (Xe.y + wXo.y) * scale);
                Sd[km] = make_float2((Xe.x - wXo.x) * scale, -(Xe.y - wXo.y) * scale);
            }
        }
    } else {
        // transpose/pack: x(B,N,D) -> zin[(d*8+b)][n'] = x[b][2n'][d] + i x[b][2n'+1][d]
        int bid = blockIdx.x - 512;
        int nt = bid & 127, dt = (bid >> 7) & 7, bb = bid >> 10;
        float* tile = (float*)sbuf;    // [64 n][65] floats
        const float4* x4 = (const float4*)(x + ((size_t)bb * 8192 + (size_t)nt * 64) * 512 + dt * 64);
        int lane4 = tid & 15, row = tid >> 4;   // row 0..31
        #pragma unroll
        for (int r = 0; r < 2; ++r) {
            int rr = row + 32 * r;
            float4 vv = x4[(size_t)rr * 128 + lane4];
            float* dst = &tile[rr * 65 + lane4 * 4];
            dst[0] = vv.x; dst[1] = vv.y; dst[2] = vv.z; dst[3] = vv.w;
        }
        __syncthreads();
        int tx4 = tid & 15, dl = tid >> 4;      // dl 0..31
        #pragma unroll
        for (int r = 0; r < 2; ++r) {
            int dloc = dl + 32 * r;
            int d = dt * 64 + dloc;
            int npb = nt * 32 + 2 * tx4;
            float4 w;
            w.x = tile[(4 * tx4 + 0) * 65 + dloc];
            w.y = tile[(4 * tx4 + 1) * 65 + dloc];
            w.z = tile[(4 * tx4 + 2) * 65 + dloc];
            w.w = tile[(4 * tx4 + 3) * 65 + dloc];
            *(float4*)&zin[((size_t)(d * 8 + bb)) * 4096 + npb] = w;
        }
    }
}

// K2: fwd FFT -> unpack*spec*repack -> inv FFT, store first half.
__global__ __launch_bounds__(512) void k2_conv(const float2* __restrict__ zin,
                                               const float2* __restrict__ spec,
                                               float2* __restrict__ yout) {
    __shared__ float2 sbuf[8192];
    int wg = blockIdx.x, d = wg >> 3, tid = threadIdx.x;
    const float2* zi = zin + (size_t)wg * 4096;
    float2 v[16];
    #pragma unroll
    for (int n1 = 0; n1 < 8; ++n1) v[n1] = zi[(n1 << 9) + tid];
    // forward L1 (upper half zero)
    fft16_half<-1>(v);
    {
        float sn, cs; __sincosf(-(PI_F / 4096.0f) * (float)tid, &sn, &cs);
        twchain(v, make_float2(cs, sn));
    }
    #pragma unroll
    for (int k1 = 0; k1 < 16; ++k1) sbuf[addr1(tid, k1)] = v[SLOT(k1)];
    __syncthreads();
    fwd_L2_L3(sbuf, tid);
    // unpack -> multiply by spec -> repack on (k, 8192-k) pairs at addr3
    const float2* S = spec + (size_t)d * SPEC_LEN;
    #pragma unroll
    for (int tt = 0; tt < 8; ++tt) {
        int k = tid + (tt << 9);
        if (k == 0) {
            float2 Z0 = sbuf[addr3(0)];
            float X0 = Z0.x + Z0.y, XM = Z0.x - Z0.y;
            float2 S0 = S[0], SM = S[8192];
            float2 Y0 = make_float2(X0 * S0.x, X0 * S0.y);
            float2 YM = make_float2(XM * SM.x, XM * SM.y);
            float2 Ye = make_float2((Y0.x + YM.x) * 0.5f, (Y0.y - YM.y) * 0.5f);
            float2 Yo = make_float2((Y0.x - YM.x) * 0.5f, (Y0.y + YM.y) * 0.5f);
            sbuf[addr3(0)] = make_float2(Ye.x - Yo.y, Ye.y + Yo.x);
            int p4 = addr3(4096);
            float2 Z4 = sbuf[p4];
            float2 Y4 = cmul(make_float2(Z4.x, -Z4.y), S[4096]);
            sbuf[p4] = make_float2(Y4.x, -Y4.y);
        } else {
            int km = 8192 - k;
            int p1 = addr3(k), p2 = addr3(km);
            float2 Zk = sbuf[p1], Zm = sbuf[p2];
            float2 Xe = make_float2((Zk.x + Zm.x) * 0.5f, (Zk.y - Zm.y) * 0.5f);
            float2 dz = make_float2((Zk.x - Zm.x) * 0.5f, (Zk.y + Zm.y) * 0.5f);
            float2 Xo = make_float2(dz.y, -dz.x);
            float sn, cs; __sincosf(-(PI_F / 8192.0f) * (float)k, &sn, &cs);
            float2 w = make_float2(cs, sn);
            float2 wXo = cmul(w, Xo);
            float2 Xk = f2add(Xe, wXo);
            float2 Xm = make_float2(Xe.x - wXo.x, -(Xe.y - wXo.y));
            float2 Yk = cmul(Xk, S[k]);
            float2 Ym = cmul(Xm, S[km]);
            float2 Ye = make_float2((Yk.x + Ym.x) * 0.5f, (Yk.y - Ym.y) * 0.5f);
            float2 dy = make_float2((Yk.x - Ym.x) * 0.5f, (Yk.y + Ym.y) * 0.5f);
            float2 Yo = cmul(make_float2(cs, -sn), dy);
            sbuf[p1] = make_float2(Ye.x - Yo.y, Ye.y + Yo.x);
            sbuf[p2] = make_float2(Ye.x + Yo.y, Yo.x - Ye.y);
        }
    }
    __syncthreads();
    inv_L3_L2(sbuf, tid);
    inv_L1(sbuf, tid, v);     // 1/8192 folded into spec
    float2* yo = yout + (size_t)wg * 4096;
    #pragma unroll
    for (int n1 = 0; n1 < 8; ++n1) yo[(n1 << 9) + tid] = v[SLOT(n1)];
}

// K3: yout[(d*8+b)][n'] -> out[b][2n'+e][d], float4 on both global sides.
__global__ __launch_bounds__(512) void k3_unpack(const float2* __restrict__ yout,
                                                 float* __restrict__ out) {
    __shared__ float2 tile[64 * 33];   // [d-local 64][np-local 32] pad 33
    int bid = blockIdx.x;
    int nt = bid & 127, dt = (bid >> 7) & 7, bb = bid >> 10;
    int tid = threadIdx.x;
    const float4* y4 = (const float4*)yout;
    int tx4 = tid & 15, dl = tid >> 4;      // dl 0..31
    #pragma unroll
    for (int r = 0; r < 2; ++r) {
        int dloc = dl + 32 * r;
        int d = dt * 64 + dloc;
        float4 vv = y4[(size_t)(d * 8 + bb) * 2048 + nt * 16 + tx4];
        tile[dloc * 33 + 2 * tx4]     = make_float2(vv.x, vv.y);
        tile[dloc * 33 + 2 * tx4 + 1] = make_float2(vv.z, vv.w);
    }
    __syncthreads();
    const float* tf = (const float*)tile;
    int lane4 = tid & 15, nl = tid >> 4;    // nl 0..31
    #pragma unroll
    for (int r = 0; r < 2; ++r) {
        int nloc = nl + 32 * r;             // 0..63
        int npl = nloc >> 1, e = nloc & 1;
        float4 w;
        w.x = tf[((4 * lane4 + 0) * 33 + npl) * 2 + e];
        w.y = tf[((4 * lane4 + 1) * 33 + npl) * 2 + e];
        w.z = tf[((4 * lane4 + 2) * 33 + npl) * 2 + e];
        w.w = tf[((4 * lane4 + 3) * 33 + npl) * 2 + e];
        int n = nt * 64 + nloc;
        *(float4*)&out[((size_t)bb * 8192 + n) * 512 + dt * 64 + lane4 * 4] = w;
    }
}

extern "C" void kernel_launch(void* const* d_in, const int* in_sizes, int n_in,
                              void* d_out, int out_size, void* d_ws, size_t ws_size,
                              hipStream_t stream) {
    const float* x      = (const float*)d_in[0];   // (8, 8192, 512)
    const float* coeffs = (const float*)d_in[1];   // (512, 512)
    const float* dc     = (const float*)d_in[2];   // (512, 1)
    float* out = (float*)d_out;                    // (8, 8192, 512)

    float2* spec = (float2*)d_ws;                                  // 512*8193 f2
    float2* zbuf = (float2*)((char*)d_ws + (size_t)512 * SPEC_LEN * sizeof(float2)); // 4096*4096 f2

    k01<<<512 + 8192, 512, 0, stream>>>(x, coeffs, dc, spec, zbuf);
    k2_conv<<<4096, 512, 0, stream>>>(zbuf, spec, zbuf);   // in-place per-wg
    k3_unpack<<<8192, 512, 0, stream>>>(zbuf, out);
}